// Round 2
// baseline (343.283 us; speedup 1.0000x reference)
//
#include <hip/hip_runtime.h>
#include <math.h>

typedef float vf4 __attribute__((ext_vector_type(4)));

constexpr int T = 8192;
constexpr int D = 128;
constexpr int N = 32;
constexpr int L = 32;            // chunk length
constexpr int LOG2L = 5;         // log2(L)
constexpr int K = T / L;         // 256 chunks
constexpr int S = N * D;         // 4096 scalar states
constexpr int S4 = S / 4;        // 1024 float4 states
constexpr int D4 = D / 4;        // 32
constexpr int OSTRIDE4 = (2 * N * D) / 4;  // 2048 float4 per output time-row

// ---------------------------------------------------------------------------
// A: per (chunk k, float4-state s4) compute chunk-local carries:
//    c_a = m_L (chunk-local EMA mean, m_0=0)
//    P   = alpha * sum_i beta^(L-i) * u_i^2,  u_i = x_i - m_i
//    cQ  = alpha * beta^L * sum_i u_i
// ---------------------------------------------------------------------------
__global__ __launch_bounds__(256) void kA_carries(
    const vf4* __restrict__ x, const vf4* __restrict__ alpha,
    vf4* __restrict__ c_a, vf4* __restrict__ c_p, vf4* __restrict__ c_q)
{
    int gid = blockIdx.x * 256 + threadIdx.x;   // [0, K*S4)
    int k   = gid >> 10;                        // gid / S4
    int s4  = gid & (S4 - 1);
    int d4  = s4 & (D4 - 1);

    vf4 a = alpha[s4];
    vf4 b = 1.0f - a;
    vf4 m  = {0.f, 0.f, 0.f, 0.f};
    vf4 p  = {0.f, 0.f, 0.f, 0.f};
    vf4 su = {0.f, 0.f, 0.f, 0.f};
    const vf4* xp = x + (size_t)k * L * D4 + d4;
#pragma unroll 8
    for (int i = 0; i < L; ++i) {
        vf4 xv = xp[(size_t)i * D4];
        vf4 u  = xv - m;
        su = su + u;
        p  = b * (p + a * u * u);
        m  = m + a * u;            // == b*m + a*xv
    }
    vf4 bl = b;
#pragma unroll
    for (int i = 0; i < LOG2L; ++i) bl *= bl;   // beta^L
    c_a[gid] = m;
    c_p[gid] = p;
    c_q[gid] = a * bl * su;
}

// ---------------------------------------------------------------------------
// B: scalar per-state scan over K chunks; produces chunk-start h_a and h_v,
//    plus the hN_a / sqrt(hN_v) tails.
// ---------------------------------------------------------------------------
__global__ __launch_bounds__(256) void kB_scan(
    const float* __restrict__ h_a0, const float* __restrict__ h_sd0,
    const float* __restrict__ alpha,
    const float* __restrict__ c_a, const float* __restrict__ c_p,
    const float* __restrict__ c_q,
    float* __restrict__ ha_st, float* __restrict__ hv_st,
    float* __restrict__ out)
{
    int s = blockIdx.x * 256 + threadIdx.x;     // [0, S)
    float a = alpha[s];
    float b = 1.0f - a;
    float bl = b;
#pragma unroll
    for (int i = 0; i < LOG2L; ++i) bl *= bl;   // beta^L
    float R = bl * (1.0f - bl);

    float ha = h_a0[s];
    float sd = h_sd0[s];
    float hv = sd * sd;
#pragma unroll 4
    for (int k = 0; k < K; ++k) {
        size_t idx = (size_t)k * S + s;
        ha_st[idx] = ha;
        hv_st[idx] = hv;
        float ca = c_a[idx];
        float p  = c_p[idx];
        float q  = c_q[idx];
        hv = bl * hv + (p - 2.0f * q * ha + R * ha * ha);
        ha = bl * ha + ca;
    }
    out[(size_t)T * 2 * N * D + s]     = ha;
    out[(size_t)T * 2 * N * D + S + s] = sqrtf(hv);
}

// ---------------------------------------------------------------------------
// C: per (chunk, float4-state): walk L steps with the exact reference
//    recurrence from the true chunk-start states; write both output halves.
// ---------------------------------------------------------------------------
__global__ __launch_bounds__(256) void kC_walk(
    const vf4* __restrict__ x, const vf4* __restrict__ alpha,
    const vf4* __restrict__ ha_st, const vf4* __restrict__ hv_st,
    vf4* __restrict__ out)
{
    int gid = blockIdx.x * 256 + threadIdx.x;
    int k   = gid >> 10;
    int s4  = gid & (S4 - 1);
    int d4  = s4 & (D4 - 1);

    vf4 a = alpha[s4];
    vf4 b = 1.0f - a;
    vf4 h = ha_st[gid];
    vf4 v = hv_st[gid];
    const vf4* xp = x + (size_t)k * L * D4 + d4;
    vf4* opa = out + (size_t)k * L * OSTRIDE4 + s4;           // out_a row slot
    vf4* opv = opa + N * D4;                                  // out_v row slot
#pragma unroll 8
    for (int i = 0; i < L; ++i) {
        vf4 xv  = xp[(size_t)i * D4];
        vf4 dx  = xv - h;            // uses OLD h (matches reference)
        vf4 adx = a * dx;
        v = b * (v + adx * dx);
        h = h + adx;
        vf4 r;
#pragma unroll
        for (int j = 0; j < 4; ++j) r[j] = sqrtf(v[j]);
        opa[(size_t)i * OSTRIDE4] = h;
        opv[(size_t)i * OSTRIDE4] = r;
    }
}

// ---------------------------------------------------------------------------
extern "C" void kernel_launch(void* const* d_in, const int* in_sizes, int n_in,
                              void* d_out, int out_size, void* d_ws, size_t ws_size,
                              hipStream_t stream) {
    const float* x     = (const float*)d_in[0];   // (T, D)
    const float* h_a0  = (const float*)d_in[1];   // (N, D)
    const float* h_sd0 = (const float*)d_in[2];   // (N, D)
    const float* alpha = (const float*)d_in[3];   // (N, D)
    float* out = (float*)d_out;                   // (T,2N,D) + tails
    float* ws  = (float*)d_ws;

    // workspace: 5 arrays of K*S floats (4 MB each, 20 MB total)
    float* c_a   = ws + 0 * (size_t)K * S;
    float* c_p   = ws + 1 * (size_t)K * S;
    float* c_q   = ws + 2 * (size_t)K * S;
    float* ha_st = ws + 3 * (size_t)K * S;
    float* hv_st = ws + 4 * (size_t)K * S;

    dim3 big(K * S4 / 256);   // 1024 blocks
    dim3 small(S / 256);      // 16 blocks
    dim3 blk(256);

    kA_carries<<<big,   blk, 0, stream>>>((const vf4*)x, (const vf4*)alpha,
                                          (vf4*)c_a, (vf4*)c_p, (vf4*)c_q);
    kB_scan   <<<small, blk, 0, stream>>>(h_a0, h_sd0, alpha, c_a, c_p, c_q,
                                          ha_st, hv_st, out);
    kC_walk   <<<big,   blk, 0, stream>>>((const vf4*)x, (const vf4*)alpha,
                                          (const vf4*)ha_st, (const vf4*)hv_st,
                                          (vf4*)out);
}